// Round 8
// baseline (176.500 us; speedup 1.0000x reference)
//
#include <hip/hip_runtime.h>

typedef __bf16 bf16;
typedef __bf16 bf16x8 __attribute__((ext_vector_type(8)));
typedef __bf16 bf16x4 __attribute__((ext_vector_type(4)));
typedef float f32x4 __attribute__((ext_vector_type(4)));

#define SCL 0.18033688011112042f  // (1/8) * log2(e), folded into q projection

#define GLOAD_LDS16(g, l)                                          \
  __builtin_amdgcn_global_load_lds(                                \
      (const __attribute__((address_space(1))) void*)(g),          \
      (__attribute__((address_space(3))) void*)(l), 16, 0, 0)

// ---------------------------------------------------------------------------
// Fused prep: fp32->bf16 convert of x (blocks 0-2047) and context (2048-3071),
// plus all 3 weight transposes W[K][N] fp32 -> Wt[N][K] bf16 (blocks 3072-4095).
// ---------------------------------------------------------------------------
__global__ __launch_bounds__(256) void prep_kernel(const float* __restrict__ x,
                                                   const float* __restrict__ ctx,
                                                   const float* __restrict__ Wq,
                                                   const float* __restrict__ Wkv,
                                                   const float* __restrict__ Wo,
                                                   bf16* __restrict__ xb,
                                                   bf16* __restrict__ cb,
                                                   bf16* __restrict__ Wqt,
                                                   bf16* __restrict__ Wkvt,
                                                   bf16* __restrict__ Wot) {
  const int bid = blockIdx.x;
  const int tid = threadIdx.x;
  if (bid < 3072) {
    const float* src;
    bf16* dst;
    size_t off;
    if (bid < 2048) { src = x; dst = xb; off = (size_t)bid * 2048; }
    else            { src = ctx; dst = cb; off = (size_t)(bid - 2048) * 2048; }
    size_t i = off + (size_t)tid * 8;
    float4 a0 = *(const float4*)&src[i];
    float4 a1 = *(const float4*)&src[i + 4];
    bf16x8 o;
    o[0] = (bf16)a0.x; o[1] = (bf16)a0.y; o[2] = (bf16)a0.z; o[3] = (bf16)a0.w;
    o[4] = (bf16)a1.x; o[5] = (bf16)a1.y; o[6] = (bf16)a1.z; o[7] = (bf16)a1.w;
    *(bf16x8*)&dst[i] = o;
  } else {
    __shared__ float tile[32][33];
    const int idx = bid - 3072;
    const int bx = idx & 63;
    const int k0 = (idx >> 6) * 32;
    const float* W; bf16* Wt; int N, n0;
    if (bx < 16)      { W = Wq;  Wt = Wqt;  N = 512;  n0 = bx * 32; }
    else if (bx < 48) { W = Wkv; Wt = Wkvt; N = 1024; n0 = (bx - 16) * 32; }
    else              { W = Wo;  Wt = Wot;  N = 512;  n0 = (bx - 48) * 32; }
    const int j = tid & 31, i0 = tid >> 5;
#pragma unroll
    for (int ii = 0; ii < 4; ii++) {
      int i = i0 * 4 + ii;
      tile[i][j] = W[(size_t)(k0 + i) * N + n0 + j];
    }
    __syncthreads();
#pragma unroll
    for (int ii = 0; ii < 4; ii++) {
      int i = i0 * 4 + ii;
      Wt[(size_t)(n0 + i) * 512 + k0 + j] = (bf16)tile[j][i];
    }
  }
}

// ---------------------------------------------------------------------------
// 128x64-tile GEMM core, K=512, BK=64, 256 threads. Wave tile 64x32.
// global_load_lds staging, source-permuted XOR swizzle. (R5/R7 proven.)
// ---------------------------------------------------------------------------
__device__ __forceinline__ void gemm128x64_core(const bf16* __restrict__ A,
                                                const bf16* __restrict__ Bt,
                                                int m0, int n0,
                                                bf16* As, bf16* Bs,
                                                f32x4 (&acc)[4][2],
                                                int wave, int lane) {
  const int l15 = lane & 15, quad = lane >> 4;
  const int psw = l15 & 7;
  const int lrow = lane >> 3;            // 0..7
  const int gchunk = (lane & 7) ^ lrow;  // swizzled source 16B-chunk
  const bf16* Ag = A + (size_t)(m0 + wave * 32 + lrow) * 512 + gchunk * 8;
  const bf16* Bg = Bt + (size_t)(n0 + wave * 16 + lrow) * 512 + gchunk * 8;
  bf16* Asw = As + wave * 32 * 64;
  bf16* Bsw = Bs + wave * 16 * 64;
  const int wm = (wave >> 1) * 64, wn = (wave & 1) * 32;

  for (int kt = 0; kt < 512; kt += 64) {
#pragma unroll
    for (int g = 0; g < 4; g++)
      GLOAD_LDS16(Ag + kt + (size_t)(g * 8) * 512, Asw + g * 8 * 64);
#pragma unroll
    for (int g = 0; g < 2; g++)
      GLOAD_LDS16(Bg + kt + (size_t)(g * 8) * 512, Bsw + g * 8 * 64);
    __syncthreads();
#pragma unroll
    for (int h = 0; h < 2; h++) {
      bf16x8 af[4], bfr[2];
#pragma unroll
      for (int i = 0; i < 4; i++)
        af[i] = *(const bf16x8*)&As[(wm + i * 16 + l15) * 64 + (((h * 4 + quad) ^ psw) * 8)];
#pragma unroll
      for (int j = 0; j < 2; j++)
        bfr[j] = *(const bf16x8*)&Bs[(wn + j * 16 + l15) * 64 + (((h * 4 + quad) ^ psw) * 8)];
#pragma unroll
      for (int i = 0; i < 4; i++)
#pragma unroll
        for (int j = 0; j < 2; j++)
          acc[i][j] = __builtin_amdgcn_mfma_f32_16x16x32_bf16(af[i], bfr[j], acc[i][j], 0, 0, 0);
    }
    __syncthreads();
  }
}

// ---------------------------------------------------------------------------
// Fused q-proj + kv-proj with XCD-aware mapping (bid%8 == m-tile%8).
// ---------------------------------------------------------------------------
__global__ __launch_bounds__(256) void proj_kernel(const bf16* __restrict__ xb,
                                                   const bf16* __restrict__ cb,
                                                   const bf16* __restrict__ Wqt,
                                                   const bf16* __restrict__ Wkvt,
                                                   bf16* __restrict__ qb,
                                                   bf16* __restrict__ Kb,
                                                   bf16* __restrict__ Vtb) {
  __shared__ __align__(16) bf16 As[128 * 64];
  __shared__ __align__(16) bf16 Bs[64 * 64];
  const int tid = threadIdx.x;
  const int wave = tid >> 6, lane = tid & 63;
  const int quad = lane >> 4, l15 = lane & 15;
  const int bid = blockIdx.x;
  f32x4 acc[4][2] = {};
  const int wm = (wave >> 1) * 64, wn = (wave & 1) * 32;

  if (bid < 512) {
    const int m0 = (bid & 63) * 128, n0 = (bid >> 6) * 64;  // XCD: bid%8 == m%8
    gemm128x64_core(xb, Wqt, m0, n0, As, Bs, acc, wave, lane);
#pragma unroll
    for (int i = 0; i < 4; i++) {
      const int rowb = m0 + wm + i * 16 + quad * 4;
#pragma unroll
      for (int j = 0; j < 2; j++) {
        const int col = n0 + wn + j * 16 + l15;
#pragma unroll
        for (int r = 0; r < 4; r++)
          qb[(size_t)(rowb + r) * 512 + col] = (bf16)(acc[i][j][r] * SCL);
      }
    }
  } else {
    const int idx = bid - 512;
    const int m0 = (idx & 31) * 128, n0 = (idx >> 5) * 64;  // XCD: bid%8 == m%8
    gemm128x64_core(cb, Wkvt, m0, n0, As, Bs, acc, wave, lane);
#pragma unroll
    for (int i = 0; i < 4; i++) {
      const int rowb = m0 + wm + i * 16 + quad * 4;
#pragma unroll
      for (int j = 0; j < 2; j++) {
        const int col = n0 + wn + j * 16 + l15;
        if (col < 512) {
#pragma unroll
          for (int r = 0; r < 4; r++)
            Kb[(size_t)(rowb + r) * 512 + col] = (bf16)acc[i][j][r];
        } else {
          const int hh = (col - 512) >> 6, d = (col - 512) & 63;
          const int bb = rowb >> 11, mb = rowb & 2047;
          bf16x4 pk;
          pk[0] = (bf16)acc[i][j][0]; pk[1] = (bf16)acc[i][j][1];
          pk[2] = (bf16)acc[i][j][2]; pk[3] = (bf16)acc[i][j][3];
          *(bf16x4*)&Vtb[((size_t)(bb * 8 + hh) * 64 + d) * 2048 + mb] = pk;
        }
      }
    }
  }
}

// ---------------------------------------------------------------------------
// Final projection: out = attn @ Wot^T + bo, fp32. 512 blocks, XCD-mapped.
// ---------------------------------------------------------------------------
__global__ __launch_bounds__(256) void outproj_kernel(const bf16* __restrict__ attn,
                                                      const bf16* __restrict__ Wot,
                                                      float* __restrict__ out,
                                                      const float* __restrict__ bias) {
  __shared__ __align__(16) bf16 As[128 * 64];
  __shared__ __align__(16) bf16 Bs[64 * 64];
  const int tid = threadIdx.x;
  const int wave = tid >> 6, lane = tid & 63;
  const int quad = lane >> 4, l15 = lane & 15;
  const int bid = blockIdx.x;
  const int m0 = (bid & 63) * 128, n0 = (bid >> 6) * 64;  // XCD: bid%8 == m%8
  f32x4 acc[4][2] = {};
  gemm128x64_core(attn, Wot, m0, n0, As, Bs, acc, wave, lane);
  const int wm = (wave >> 1) * 64, wn = (wave & 1) * 32;
#pragma unroll
  for (int i = 0; i < 4; i++) {
    const int rowb = m0 + wm + i * 16 + quad * 4;
#pragma unroll
    for (int j = 0; j < 2; j++) {
      const int col = n0 + wn + j * 16 + l15;
      const float bv = bias[col];
#pragma unroll
      for (int r = 0; r < 4; r++)
        out[(size_t)(rowb + r) * 512 + col] = acc[i][j][r] + bv;
    }
  }
}

// ---------------------------------------------------------------------------
// Flash attention. R5 structure: Sᵀ formulation, W=32 q-cols/wave (128 q-rows
// per WG), grid 512 (2 WG/CU). XCD grouping: (b,h) = bid&15 so each XCD's L2
// holds only 2 K/V sets. K: LDS double-buffered, register-prefetched 1 tile
// ahead. V: NEVER in LDS — per-wave fragments prefetched global->VGPR one
// full tile ahead (~1300 cyc before use), served from XCD-local L2.
// ---------------------------------------------------------------------------
__global__ __launch_bounds__(256, 2) void attn_kernel(const bf16* __restrict__ q,
                                                      const bf16* __restrict__ Kb,
                                                      const bf16* __restrict__ Vtb,
                                                      bf16* __restrict__ attn_out) {
  const int tid = threadIdx.x;
  const int wave = tid >> 6, lane = tid & 63;
  const int quad = lane >> 4, l15 = lane & 15;
  const int bid = blockIdx.x;
  // XCD grouping: same (b,h) -> same bid mod 16 -> same XCD (mod 8)
  const int g = bid & 15, inner = bid >> 4;   // inner in [0,32)
  const int b = g >> 3, h = g & 7;
  const int s = inner & 3, nt = inner >> 2;   // nt in [0,8)
  const int n0 = nt * 128;

  __shared__ __align__(16) bf16 Kl[2][64 * 64];
  __shared__ __align__(16) bf16 Pl[4][32 * 64];
  bf16* Pw = &Pl[wave][0];

  // Q B-fragments for the wave's two 16-col groups (SCL pre-applied)
  size_t qoff[2];
  bf16x8 qf[2][2];
#pragma unroll
  for (int cg = 0; cg < 2; cg++) {
    const int n = n0 + wave * 32 + cg * 16 + l15;
    qoff[cg] = ((size_t)((b * 1024 + n) * 4 + s)) * 512 + h * 64;
    qf[cg][0] = *(const bf16x8*)&q[qoff[cg] + quad * 8];
    qf[cg][1] = *(const bf16x8*)&q[qoff[cg] + 32 + quad * 8];
  }

  f32x4 o[2][4] = {};
  f32x4 ol[2] = {};
  bf16x8 ones;
#pragma unroll
  for (int i = 0; i < 8; i++) ones[i] = (bf16)1.0f;

  // K staging: thread -> row (tid>>2), 16B chunks 2*(tid&3), 2*(tid&3)+1
  const int srow = tid >> 2, c0 = tid & 3;
  const bf16* Kg = Kb + (size_t)(b * 2048 + srow) * 512 + h * 64 + c0 * 16;
  const int ssw = srow & 7;
  const int koff0 = srow * 64 + ((c0 * 2) ^ ssw) * 8;
  const int koff1 = srow * 64 + ((c0 * 2 + 1) ^ ssw) * 8;

  uint4 kr0 = *(const uint4*)Kg;
  uint4 kr1 = *(const uint4*)(Kg + 8);
  *(uint4*)&Kl[0][koff0] = kr0;
  *(uint4*)&Kl[0][koff1] = kr1;

  // V fragment base: row d = dg*16 + l15, col m = t*64 + mch*32 + quad*8
  const bf16* vbase = Vtb + ((size_t)(b * 8 + h) * 64 + l15) * 2048 + quad * 8;

  // V fragments for tile 0
  bf16x8 vcur[4][2], vnxt[4][2];
#pragma unroll
  for (int dg = 0; dg < 4; dg++)
#pragma unroll
    for (int mch = 0; mch < 2; mch++)
      vcur[dg][mch] = *(const bf16x8*)(vbase + (size_t)(dg * 16) * 2048 + mch * 32);

  const int psw = l15 & 7;

  for (int t = 0; t < 32; ++t) {
    __syncthreads();
    if (t < 31) {
      // prefetch V fragments for tile t+1 (consumed next iteration)
#pragma unroll
      for (int dg = 0; dg < 4; dg++)
#pragma unroll
        for (int mch = 0; mch < 2; mch++)
          vnxt[dg][mch] = *(const bf16x8*)(vbase + (size_t)(dg * 16) * 2048 + (t + 1) * 64 + mch * 32);
      // prefetch K tile t+1 into registers (stored to LDS at end of body)
      const bf16* kg = Kg + (size_t)(t + 1) * 64 * 512;
      kr0 = *(const uint4*)kg;
      kr1 = *(const uint4*)(kg + 8);
    }
    const bf16* Kc = &Kl[t & 1][0];

    // Sᵀ: sf[cg][mc][r] = Sᵀ[m = mc*16+quad*4+r][n-group cg]  (exp2 domain)
    f32x4 sf[2][4];
#pragma unroll
    for (int mc = 0; mc < 4; mc++) {
      bf16x8 kf0 = *(const bf16x8*)&Kc[(mc * 16 + l15) * 64 + ((quad ^ psw) * 8)];
      bf16x8 kf1 = *(const bf16x8*)&Kc[(mc * 16 + l15) * 64 + (((4 + quad) ^ psw) * 8)];
#pragma unroll
      for (int cg = 0; cg < 2; cg++) {
        f32x4 z = {};
        z = __builtin_amdgcn_mfma_f32_16x16x32_bf16(kf0, qf[cg][0], z, 0, 0, 0);
        z = __builtin_amdgcn_mfma_f32_16x16x32_bf16(kf1, qf[cg][1], z, 0, 0, 0);
        sf[cg][mc] = z;
      }
    }

    // exp2 numerators -> Pᵀ in LDS as P[n_local][m], swizzled (wave-local)
#pragma unroll
    for (int cg = 0; cg < 2; cg++)
#pragma unroll
      for (int mc = 0; mc < 4; mc++) {
        bf16x4 pk;
        pk[0] = (bf16)__builtin_amdgcn_exp2f(sf[cg][mc][0]);
        pk[1] = (bf16)__builtin_amdgcn_exp2f(sf[cg][mc][1]);
        pk[2] = (bf16)__builtin_amdgcn_exp2f(sf[cg][mc][2]);
        pk[3] = (bf16)__builtin_amdgcn_exp2f(sf[cg][mc][3]);
        *(bf16x4*)&Pw[(cg * 16 + l15) * 64 + (((mc * 2 + (quad >> 1)) ^ psw)) * 8 + (quad & 1) * 4] = pk;
      }

    // Oᵀ += Vᵀ·Pᵀ (V from registers) ; l += 1ᵀ·Pᵀ (ones-row MFMA)
#pragma unroll
    for (int mch = 0; mch < 2; mch++) {
      bf16x8 pf[2];
#pragma unroll
      for (int cg = 0; cg < 2; cg++)
        pf[cg] = *(const bf16x8*)&Pw[(cg * 16 + l15) * 64 + (((mch * 4 + quad) ^ psw)) * 8];
#pragma unroll
      for (int dg = 0; dg < 4; dg++)
#pragma unroll
        for (int cg = 0; cg < 2; cg++)
          o[cg][dg] = __builtin_amdgcn_mfma_f32_16x16x32_bf16(vcur[dg][mch], pf[cg], o[cg][dg], 0, 0, 0);
#pragma unroll
      for (int cg = 0; cg < 2; cg++)
        ol[cg] = __builtin_amdgcn_mfma_f32_16x16x32_bf16(ones, pf[cg], ol[cg], 0, 0, 0);
    }

    // rotate buffers: K regs -> LDS, V next -> cur
    if (t < 31) {
      bf16* Kn = &Kl[(t + 1) & 1][0];
      *(uint4*)&Kn[koff0] = kr0;
      *(uint4*)&Kn[koff1] = kr1;
#pragma unroll
      for (int dg = 0; dg < 4; dg++)
#pragma unroll
        for (int mch = 0; mch < 2; mch++)
          vcur[dg][mch] = vnxt[dg][mch];
    }
  }

  // epilogue: l[n] = any row of ol[cg]; normalize, pack 8B stores
#pragma unroll
  for (int cg = 0; cg < 2; cg++) {
    const float inv = 1.0f / ol[cg][0];
#pragma unroll
    for (int dg = 0; dg < 4; dg++) {
      bf16x4 ok;
      ok[0] = (bf16)(o[cg][dg][0] * inv); ok[1] = (bf16)(o[cg][dg][1] * inv);
      ok[2] = (bf16)(o[cg][dg][2] * inv); ok[3] = (bf16)(o[cg][dg][3] * inv);
      *(bf16x4*)&attn_out[qoff[cg] + dg * 16 + quad * 4] = ok;
    }
  }
}

// ---------------------------------------------------------------------------
extern "C" void kernel_launch(void* const* d_in, const int* in_sizes, int n_in,
                              void* d_out, int out_size, void* d_ws, size_t ws_size,
                              hipStream_t stream) {
  const float* x = (const float*)d_in[0];
  const float* context = (const float*)d_in[1];
  const float* Wq = (const float*)d_in[2];
  const float* Wkv = (const float*)d_in[3];
  const float* Wo = (const float*)d_in[4];
  const float* bo = (const float*)d_in[5];
  float* out = (float*)d_out;

  char* ws = (char*)d_ws;
  bf16* xb   = (bf16*)(ws);                         // 8 MB (reused as attn)
  bf16* cb   = (bf16*)(ws + (8u << 20));            // 4 MB
  bf16* qb   = (bf16*)(ws + (12u << 20));           // 8 MB
  bf16* Kb   = (bf16*)(ws + (20u << 20));           // 4 MB
  bf16* Vtb  = (bf16*)(ws + (24u << 20));           // 4 MB
  bf16* Wqt  = (bf16*)(ws + (28u << 20));           // 512 KB
  bf16* Wkvt = (bf16*)(ws + (28u << 20) + 524288);  // 1 MB
  bf16* Wot  = (bf16*)(ws + (28u << 20) + 1572864); // 512 KB
  bf16* attn = xb;  // xb dead after q-proj

  prep_kernel<<<4096, 256, 0, stream>>>(x, context, Wq, Wkv, Wo, xb, cb, Wqt, Wkvt, Wot);
  proj_kernel<<<1024, 256, 0, stream>>>(xb, cb, Wqt, Wkvt, qb, Kb, Vtb);
  attn_kernel<<<512, 256, 0, stream>>>(qb, Kb, Vtb, attn);
  outproj_kernel<<<512, 256, 0, stream>>>(attn, Wot, out, bo);
}

// Round 9
// 152.879 us; speedup vs baseline: 1.1545x; 1.1545x over previous
//
#include <hip/hip_runtime.h>

typedef __bf16 bf16;
typedef __bf16 bf16x8 __attribute__((ext_vector_type(8)));
typedef __bf16 bf16x4 __attribute__((ext_vector_type(4)));
typedef float f32x4 __attribute__((ext_vector_type(4)));

#define SCL 0.18033688011112042f  // (1/8) * log2(e), folded into q projection

#define GLOAD_LDS16(g, l)                                          \
  __builtin_amdgcn_global_load_lds(                                \
      (const __attribute__((address_space(1))) void*)(g),          \
      (__attribute__((address_space(3))) void*)(l), 16, 0, 0)

// ---------------------------------------------------------------------------
// Fused prep: fp32->bf16 convert of x (blocks 0-2047) and context (2048-3071),
// plus all 3 weight transposes W[K][N] fp32 -> Wt[N][K] bf16 (blocks 3072-4095).
// ---------------------------------------------------------------------------
__global__ __launch_bounds__(256) void prep_kernel(const float* __restrict__ x,
                                                   const float* __restrict__ ctx,
                                                   const float* __restrict__ Wq,
                                                   const float* __restrict__ Wkv,
                                                   const float* __restrict__ Wo,
                                                   bf16* __restrict__ xb,
                                                   bf16* __restrict__ cb,
                                                   bf16* __restrict__ Wqt,
                                                   bf16* __restrict__ Wkvt,
                                                   bf16* __restrict__ Wot) {
  const int bid = blockIdx.x;
  const int tid = threadIdx.x;
  if (bid < 3072) {
    const float* src;
    bf16* dst;
    size_t off;
    if (bid < 2048) { src = x; dst = xb; off = (size_t)bid * 2048; }
    else            { src = ctx; dst = cb; off = (size_t)(bid - 2048) * 2048; }
    size_t i = off + (size_t)tid * 8;
    float4 a0 = *(const float4*)&src[i];
    float4 a1 = *(const float4*)&src[i + 4];
    bf16x8 o;
    o[0] = (bf16)a0.x; o[1] = (bf16)a0.y; o[2] = (bf16)a0.z; o[3] = (bf16)a0.w;
    o[4] = (bf16)a1.x; o[5] = (bf16)a1.y; o[6] = (bf16)a1.z; o[7] = (bf16)a1.w;
    *(bf16x8*)&dst[i] = o;
  } else {
    __shared__ float tile[32][33];
    const int idx = bid - 3072;
    const int bx = idx & 63;
    const int k0 = (idx >> 6) * 32;
    const float* W; bf16* Wt; int N, n0;
    if (bx < 16)      { W = Wq;  Wt = Wqt;  N = 512;  n0 = bx * 32; }
    else if (bx < 48) { W = Wkv; Wt = Wkvt; N = 1024; n0 = (bx - 16) * 32; }
    else              { W = Wo;  Wt = Wot;  N = 512;  n0 = (bx - 48) * 32; }
    const int j = tid & 31, i0 = tid >> 5;
#pragma unroll
    for (int ii = 0; ii < 4; ii++) {
      int i = i0 * 4 + ii;
      tile[i][j] = W[(size_t)(k0 + i) * N + n0 + j];
    }
    __syncthreads();
#pragma unroll
    for (int ii = 0; ii < 4; ii++) {
      int i = i0 * 4 + ii;
      Wt[(size_t)(n0 + i) * 512 + k0 + j] = (bf16)tile[j][i];
    }
  }
}

// ---------------------------------------------------------------------------
// 128x64-tile GEMM core, K=512, BK=64, 256 threads. Wave tile 64x32.
// global_load_lds staging, source-permuted XOR swizzle. (R5/R7 proven.)
// ---------------------------------------------------------------------------
__device__ __forceinline__ void gemm128x64_core(const bf16* __restrict__ A,
                                                const bf16* __restrict__ Bt,
                                                int m0, int n0,
                                                bf16* As, bf16* Bs,
                                                f32x4 (&acc)[4][2],
                                                int wave, int lane) {
  const int l15 = lane & 15, quad = lane >> 4;
  const int psw = l15 & 7;
  const int lrow = lane >> 3;            // 0..7
  const int gchunk = (lane & 7) ^ lrow;  // swizzled source 16B-chunk
  const bf16* Ag = A + (size_t)(m0 + wave * 32 + lrow) * 512 + gchunk * 8;
  const bf16* Bg = Bt + (size_t)(n0 + wave * 16 + lrow) * 512 + gchunk * 8;
  bf16* Asw = As + wave * 32 * 64;
  bf16* Bsw = Bs + wave * 16 * 64;
  const int wm = (wave >> 1) * 64, wn = (wave & 1) * 32;

  for (int kt = 0; kt < 512; kt += 64) {
#pragma unroll
    for (int g = 0; g < 4; g++)
      GLOAD_LDS16(Ag + kt + (size_t)(g * 8) * 512, Asw + g * 8 * 64);
#pragma unroll
    for (int g = 0; g < 2; g++)
      GLOAD_LDS16(Bg + kt + (size_t)(g * 8) * 512, Bsw + g * 8 * 64);
    __syncthreads();
#pragma unroll
    for (int h = 0; h < 2; h++) {
      bf16x8 af[4], bfr[2];
#pragma unroll
      for (int i = 0; i < 4; i++)
        af[i] = *(const bf16x8*)&As[(wm + i * 16 + l15) * 64 + (((h * 4 + quad) ^ psw) * 8)];
#pragma unroll
      for (int j = 0; j < 2; j++)
        bfr[j] = *(const bf16x8*)&Bs[(wn + j * 16 + l15) * 64 + (((h * 4 + quad) ^ psw) * 8)];
#pragma unroll
      for (int i = 0; i < 4; i++)
#pragma unroll
        for (int j = 0; j < 2; j++)
          acc[i][j] = __builtin_amdgcn_mfma_f32_16x16x32_bf16(af[i], bfr[j], acc[i][j], 0, 0, 0);
    }
    __syncthreads();
  }
}

// ---------------------------------------------------------------------------
// Fused q-proj + kv-proj with XCD-aware mapping (bid%8 == m-tile%8).
// ---------------------------------------------------------------------------
__global__ __launch_bounds__(256, 2) void proj_kernel(const bf16* __restrict__ xb,
                                                      const bf16* __restrict__ cb,
                                                      const bf16* __restrict__ Wqt,
                                                      const bf16* __restrict__ Wkvt,
                                                      bf16* __restrict__ qb,
                                                      bf16* __restrict__ Kb,
                                                      bf16* __restrict__ Vtb) {
  __shared__ __align__(16) bf16 As[128 * 64];
  __shared__ __align__(16) bf16 Bs[64 * 64];
  const int tid = threadIdx.x;
  const int wave = tid >> 6, lane = tid & 63;
  const int quad = lane >> 4, l15 = lane & 15;
  const int bid = blockIdx.x;
  f32x4 acc[4][2] = {};
  const int wm = (wave >> 1) * 64, wn = (wave & 1) * 32;

  if (bid < 512) {
    const int m0 = (bid & 63) * 128, n0 = (bid >> 6) * 64;  // XCD: bid%8 == m%8
    gemm128x64_core(xb, Wqt, m0, n0, As, Bs, acc, wave, lane);
#pragma unroll
    for (int i = 0; i < 4; i++) {
      const int rowb = m0 + wm + i * 16 + quad * 4;
#pragma unroll
      for (int j = 0; j < 2; j++) {
        const int col = n0 + wn + j * 16 + l15;
#pragma unroll
        for (int r = 0; r < 4; r++)
          qb[(size_t)(rowb + r) * 512 + col] = (bf16)(acc[i][j][r] * SCL);
      }
    }
  } else {
    const int idx = bid - 512;
    const int m0 = (idx & 31) * 128, n0 = (idx >> 5) * 64;  // XCD: bid%8 == m%8
    gemm128x64_core(cb, Wkvt, m0, n0, As, Bs, acc, wave, lane);
#pragma unroll
    for (int i = 0; i < 4; i++) {
      const int rowb = m0 + wm + i * 16 + quad * 4;
#pragma unroll
      for (int j = 0; j < 2; j++) {
        const int col = n0 + wn + j * 16 + l15;
        if (col < 512) {
#pragma unroll
          for (int r = 0; r < 4; r++)
            Kb[(size_t)(rowb + r) * 512 + col] = (bf16)acc[i][j][r];
        } else {
          const int hh = (col - 512) >> 6, d = (col - 512) & 63;
          const int bb = rowb >> 11, mb = rowb & 2047;
          bf16x4 pk;
          pk[0] = (bf16)acc[i][j][0]; pk[1] = (bf16)acc[i][j][1];
          pk[2] = (bf16)acc[i][j][2]; pk[3] = (bf16)acc[i][j][3];
          *(bf16x4*)&Vtb[((size_t)(bb * 8 + hh) * 64 + d) * 2048 + mb] = pk;
        }
      }
    }
  }
}

// ---------------------------------------------------------------------------
// Final projection: out = attn @ Wot^T + bo, fp32. 512 blocks, XCD-mapped.
// ---------------------------------------------------------------------------
__global__ __launch_bounds__(256, 2) void outproj_kernel(const bf16* __restrict__ attn,
                                                         const bf16* __restrict__ Wot,
                                                         float* __restrict__ out,
                                                         const float* __restrict__ bias) {
  __shared__ __align__(16) bf16 As[128 * 64];
  __shared__ __align__(16) bf16 Bs[64 * 64];
  const int tid = threadIdx.x;
  const int wave = tid >> 6, lane = tid & 63;
  const int quad = lane >> 4, l15 = lane & 15;
  const int bid = blockIdx.x;
  const int m0 = (bid & 63) * 128, n0 = (bid >> 6) * 64;  // XCD: bid%8 == m%8
  f32x4 acc[4][2] = {};
  gemm128x64_core(attn, Wot, m0, n0, As, Bs, acc, wave, lane);
  const int wm = (wave >> 1) * 64, wn = (wave & 1) * 32;
#pragma unroll
  for (int i = 0; i < 4; i++) {
    const int rowb = m0 + wm + i * 16 + quad * 4;
#pragma unroll
    for (int j = 0; j < 2; j++) {
      const int col = n0 + wn + j * 16 + l15;
      const float bv = bias[col];
#pragma unroll
      for (int r = 0; r < 4; r++)
        out[(size_t)(rowb + r) * 512 + col] = acc[i][j][r] + bv;
    }
  }
}

// ---------------------------------------------------------------------------
// Flash attention — exact R5 structure (best measured: 55.2 µs), plus R8's
// XCD-grouped bid decode. Sᵀ formulation, W=32 q-cols/wave (128 q-rows/WG),
// grid 512 (2 WG/CU). K AND V LDS double-buffered (shared by all 4 waves),
// register-prefetched one full tile ahead. P wave-local LDS round trip.
// no-max softmax; l via ones-row MFMA.
// ---------------------------------------------------------------------------
__global__ __launch_bounds__(256, 2) void attn_kernel(const bf16* __restrict__ q,
                                                      const bf16* __restrict__ Kb,
                                                      const bf16* __restrict__ Vtb,
                                                      bf16* __restrict__ attn_out) {
  const int tid = threadIdx.x;
  const int wave = tid >> 6, lane = tid & 63;
  const int quad = lane >> 4, l15 = lane & 15;
  const int bid = blockIdx.x;
  // XCD grouping: same (b,h) -> same bid mod 16 -> same XCD (mod 8)
  const int g = bid & 15, inner = bid >> 4;   // inner in [0,32)
  const int b = g >> 3, h = g & 7;
  const int s = inner & 3, nt = inner >> 2;   // nt in [0,8)
  const int n0 = nt * 128;

  __shared__ __align__(16) bf16 Kl[2][64 * 64];
  __shared__ __align__(16) bf16 Vl[2][64 * 64];
  __shared__ __align__(16) bf16 Pl[4][32 * 64];
  bf16* Pw = &Pl[wave][0];

  // Q B-fragments for the wave's two 16-col groups (SCL pre-applied)
  size_t qoff[2];
  bf16x8 qf[2][2];
#pragma unroll
  for (int cg = 0; cg < 2; cg++) {
    const int n = n0 + wave * 32 + cg * 16 + l15;
    qoff[cg] = ((size_t)((b * 1024 + n) * 4 + s)) * 512 + h * 64;
    qf[cg][0] = *(const bf16x8*)&q[qoff[cg] + quad * 8];
    qf[cg][1] = *(const bf16x8*)&q[qoff[cg] + 32 + quad * 8];
  }

  f32x4 o[2][4] = {};
  f32x4 ol[2] = {};
  bf16x8 ones;
#pragma unroll
  for (int i = 0; i < 8; i++) ones[i] = (bf16)1.0f;

  // staging: thread -> row (tid>>2), 16B chunks 2*(tid&3), 2*(tid&3)+1
  const int srow = tid >> 2, c0 = tid & 3;
  const bf16* Kg = Kb + (size_t)(b * 2048 + srow) * 512 + h * 64 + c0 * 16;
  const bf16* Vg = Vtb + ((size_t)(b * 8 + h) * 64 + srow) * 2048 + c0 * 16;
  const int ssw = srow & 7;
  const int koff0 = srow * 64 + ((c0 * 2) ^ ssw) * 8;
  const int koff1 = srow * 64 + ((c0 * 2 + 1) ^ ssw) * 8;

  uint4 kr0 = *(const uint4*)Kg;
  uint4 kr1 = *(const uint4*)(Kg + 8);
  uint4 vr0 = *(const uint4*)Vg;
  uint4 vr1 = *(const uint4*)(Vg + 8);
  *(uint4*)&Kl[0][koff0] = kr0; *(uint4*)&Kl[0][koff1] = kr1;
  *(uint4*)&Vl[0][koff0] = vr0; *(uint4*)&Vl[0][koff1] = vr1;

  const int psw = l15 & 7;

  for (int t = 0; t < 32; ++t) {
    __syncthreads();
    if (t < 31) {
      const bf16* kg = Kg + (size_t)(t + 1) * 64 * 512;
      const bf16* vg = Vg + (t + 1) * 64;
      kr0 = *(const uint4*)kg; kr1 = *(const uint4*)(kg + 8);
      vr0 = *(const uint4*)vg; vr1 = *(const uint4*)(vg + 8);
    }
    const bf16* Kc = &Kl[t & 1][0];
    const bf16* Vc = &Vl[t & 1][0];

    // Sᵀ: sf[cg][mc][r] = Sᵀ[m = mc*16+quad*4+r][n-group cg]  (exp2 domain)
    f32x4 sf[2][4];
#pragma unroll
    for (int mc = 0; mc < 4; mc++) {
      bf16x8 kf0 = *(const bf16x8*)&Kc[(mc * 16 + l15) * 64 + ((quad ^ psw) * 8)];
      bf16x8 kf1 = *(const bf16x8*)&Kc[(mc * 16 + l15) * 64 + (((4 + quad) ^ psw) * 8)];
#pragma unroll
      for (int cg = 0; cg < 2; cg++) {
        f32x4 z = {};
        z = __builtin_amdgcn_mfma_f32_16x16x32_bf16(kf0, qf[cg][0], z, 0, 0, 0);
        z = __builtin_amdgcn_mfma_f32_16x16x32_bf16(kf1, qf[cg][1], z, 0, 0, 0);
        sf[cg][mc] = z;
      }
    }

    // exp2 numerators -> Pᵀ in LDS as P[n_local][m], swizzled (wave-local)
#pragma unroll
    for (int cg = 0; cg < 2; cg++)
#pragma unroll
      for (int mc = 0; mc < 4; mc++) {
        bf16x4 pk;
        pk[0] = (bf16)__builtin_amdgcn_exp2f(sf[cg][mc][0]);
        pk[1] = (bf16)__builtin_amdgcn_exp2f(sf[cg][mc][1]);
        pk[2] = (bf16)__builtin_amdgcn_exp2f(sf[cg][mc][2]);
        pk[3] = (bf16)__builtin_amdgcn_exp2f(sf[cg][mc][3]);
        *(bf16x4*)&Pw[(cg * 16 + l15) * 64 + (((mc * 2 + (quad >> 1)) ^ psw)) * 8 + (quad & 1) * 4] = pk;
      }

    // Oᵀ += Vᵀ·Pᵀ ; l += 1ᵀ·Pᵀ (ones-row MFMA)
#pragma unroll
    for (int mch = 0; mch < 2; mch++) {
      bf16x8 pf[2];
#pragma unroll
      for (int cg = 0; cg < 2; cg++)
        pf[cg] = *(const bf16x8*)&Pw[(cg * 16 + l15) * 64 + (((mch * 4 + quad) ^ psw)) * 8];
#pragma unroll
      for (int dg = 0; dg < 4; dg++) {
        bf16x8 vf = *(const bf16x8*)&Vc[(dg * 16 + l15) * 64 + (((mch * 4 + quad) ^ psw)) * 8];
#pragma unroll
        for (int cg = 0; cg < 2; cg++)
          o[cg][dg] = __builtin_amdgcn_mfma_f32_16x16x32_bf16(vf, pf[cg], o[cg][dg], 0, 0, 0);
      }
#pragma unroll
      for (int cg = 0; cg < 2; cg++)
        ol[cg] = __builtin_amdgcn_mfma_f32_16x16x32_bf16(ones, pf[cg], ol[cg], 0, 0, 0);
    }

    // stage tile t+1 into the other LDS buffer
    if (t < 31) {
      bf16* Kn = &Kl[(t + 1) & 1][0];
      bf16* Vn = &Vl[(t + 1) & 1][0];
      *(uint4*)&Kn[koff0] = kr0; *(uint4*)&Kn[koff1] = kr1;
      *(uint4*)&Vn[koff0] = vr0; *(uint4*)&Vn[koff1] = vr1;
    }
  }

  // epilogue: l[n] = any row of ol[cg]; normalize, pack 8B stores
#pragma unroll
  for (int cg = 0; cg < 2; cg++) {
    const float inv = 1.0f / ol[cg][0];
#pragma unroll
    for (int dg = 0; dg < 4; dg++) {
      bf16x4 ok;
      ok[0] = (bf16)(o[cg][dg][0] * inv); ok[1] = (bf16)(o[cg][dg][1] * inv);
      ok[2] = (bf16)(o[cg][dg][2] * inv); ok[3] = (bf16)(o[cg][dg][3] * inv);
      *(bf16x4*)&attn_out[qoff[cg] + dg * 16 + quad * 4] = ok;
    }
  }
}

// ---------------------------------------------------------------------------
extern "C" void kernel_launch(void* const* d_in, const int* in_sizes, int n_in,
                              void* d_out, int out_size, void* d_ws, size_t ws_size,
                              hipStream_t stream) {
  const float* x = (const float*)d_in[0];
  const float* context = (const float*)d_in[1];
  const float* Wq = (const float*)d_in[2];
  const float* Wkv = (const float*)d_in[3];
  const float* Wo = (const float*)d_in[4];
  const float* bo = (const float*)d_in[5];
  float* out = (float*)d_out;

  char* ws = (char*)d_ws;
  bf16* xb   = (bf16*)(ws);                         // 8 MB (reused as attn)
  bf16* cb   = (bf16*)(ws + (8u << 20));            // 4 MB
  bf16* qb   = (bf16*)(ws + (12u << 20));           // 8 MB
  bf16* Kb   = (bf16*)(ws + (20u << 20));           // 4 MB
  bf16* Vtb  = (bf16*)(ws + (24u << 20));           // 4 MB
  bf16* Wqt  = (bf16*)(ws + (28u << 20));           // 512 KB
  bf16* Wkvt = (bf16*)(ws + (28u << 20) + 524288);  // 1 MB
  bf16* Wot  = (bf16*)(ws + (28u << 20) + 1572864); // 512 KB
  bf16* attn = xb;  // xb dead after q-proj

  prep_kernel<<<4096, 256, 0, stream>>>(x, context, Wq, Wkv, Wo, xb, cb, Wqt, Wkvt, Wot);
  proj_kernel<<<1024, 256, 0, stream>>>(xb, cb, Wqt, Wkvt, qb, Kb, Vtb);
  attn_kernel<<<512, 256, 0, stream>>>(qb, Kb, Vtb, attn);
  outproj_kernel<<<512, 256, 0, stream>>>(attn, Wot, out, bo);
}